// Round 1
// baseline (111.285 us; speedup 1.0000x reference)
//
#include <hip/hip_runtime.h>
#include <hip/hip_bf16.h>

typedef __attribute__((ext_vector_type(8))) short short8;
typedef __attribute__((ext_vector_type(4))) float f32x4;

#define TEMP_INV 20.0f
#define NQC 512   // queue chunks of 128 rows
#define NKB 256   // keys single-column blocks
#define NCH 768   // total partial chunks

__device__ inline unsigned short f2bf(float f){
    unsigned int u = __builtin_bit_cast(unsigned int, f);
    u += 0x7fffu + ((u >> 16) & 1u);
    return (unsigned short)(u >> 16);
}
__device__ inline float bf2f(unsigned short h){
    unsigned int u = ((unsigned int)h) << 16;
    return __builtin_bit_cast(float, u);
}

// ---------------------------------------------------------------------------
// k_norm: normalize query rows -> (a) bf16 A, pre-swizzled per-64-col K-chunk
// tiles [12][256][64] so k_main can global_load_lds linearly; (b) bf16 qn^T
// [768][256] for the keys (sim_pos) blocks' coalesced column reads.
// ---------------------------------------------------------------------------
__global__ __launch_bounds__(256) void k_norm(const float* __restrict__ q,
                                              unsigned short* __restrict__ Aswz,
                                              unsigned short* __restrict__ qnT){
    int b = blockIdx.x, t = threadIdx.x;
    const float* qr = q + b * 768;
    float v0 = qr[t], v1 = qr[t + 256], v2 = qr[t + 512];
    float ss = v0*v0 + v1*v1 + v2*v2;
#pragma unroll
    for (int o = 32; o; o >>= 1) ss += __shfl_xor(ss, o);
    __shared__ float red[4];
    if ((t & 63) == 0) red[t >> 6] = ss;
    __syncthreads();
    ss = red[0] + red[1] + red[2] + red[3];
    float inv = 1.0f / fmaxf(sqrtf(ss), 1e-8f);
    float nv[3] = {v0 * inv, v1 * inv, v2 * inv};
#pragma unroll
    for (int j = 0; j < 3; j++){
        int c = t + 256 * j;
        unsigned short h = f2bf(nv[j]);
        int kc = c >> 6, kl = c & 63, g = kl >> 3, e = kl & 7;
        int slot = g ^ (b & 7);
        Aswz[kc * 16384 + b * 64 + slot * 8 + e] = h;
        qnT[c * 256 + b] = h;
    }
}

// ---------------------------------------------------------------------------
// k_main: grid = 768 blocks, 512 threads.
//   bid % 3 == 2  -> keys block kr=bid/3: one key column, VALU dots vs qnT,
//                    writes pmax[512+kr][:] = logits, psum = 1, diag[kr].
//   else          -> queue chunk qc: 256x128 MFMA tile, on-the-fly row-norm,
//                    per-chunk online-softmax partials (max, sumexp).
// ---------------------------------------------------------------------------
__global__ __launch_bounds__(512) void k_main(const float* __restrict__ keys,
                                              const float* __restrict__ queue,
                                              const unsigned short* __restrict__ Aswz,
                                              const unsigned short* __restrict__ qnT,
                                              float* __restrict__ pmax,
                                              float* __restrict__ psum,
                                              float* __restrict__ diag){
    __shared__ unsigned short Atile[256 * 64];   // 32 KB
    __shared__ unsigned short Btile[128 * 64];   // 16 KB
    __shared__ float invn[128];
    __shared__ float redm[2][256];
    __shared__ float reds[2][256];

    int bid = blockIdx.x;
    int t = threadIdx.x;
    int mod3 = bid % 3;

    if (mod3 == 2){
        // ---- keys path: one key row vs all 256 normalized queries ----
        int kr = bid / 3;
        float* klds = (float*)Atile;            // 3 KB reuse
        const float* krow = keys + kr * 768;
        float ssp = 0.f;
        for (int i = t; i < 768; i += 512){ float v = krow[i]; klds[i] = v; ssp += v * v; }
#pragma unroll
        for (int o = 32; o; o >>= 1) ssp += __shfl_xor(ssp, o);
        if ((t & 63) == 0) reds[0][t >> 6] = ssp;
        __syncthreads();
        float ssk = 0.f;
#pragma unroll
        for (int w = 0; w < 8; w++) ssk += reds[0][w];
        float invk = 1.0f / fmaxf(sqrtf(ssk), 1e-8f);
        if (t < 256){
            float dot = 0.f;
#pragma unroll 4
            for (int i = 0; i < 768; i++)
                dot += bf2f(qnT[i * 256 + t]) * klds[i];
            float logit = dot * invk * TEMP_INV;
            pmax[(NQC + kr) * 256 + t] = logit;
            psum[(NQC + kr) * 256 + t] = 1.0f;
            if (t == kr) diag[kr] = logit;
        }
        return;
    }

    // ---- queue path ----
    int qc = 2 * (bid / 3) + mod3;              // 0..511
    const float* rowp = queue + (size_t)qc * 98304 + (size_t)(t >> 2) * 768;
    int r = t >> 2, q4 = t & 3;
    int lane = t & 63, wid = t >> 6;
    int wm = wid >> 1, wn = wid & 1;            // 4 (M) x 2 (N) waves, 64x64 each
    int frow = lane & 15, fg = lane >> 4;

    float ssq = 0.f;
    f32x4 acc[4][4];
#pragma unroll
    for (int i = 0; i < 4; i++)
#pragma unroll
        for (int j = 0; j < 4; j++) acc[i][j] = (f32x4)0.f;

    for (int kc = 0; kc < 12; kc++){
        if (kc) __syncthreads();
        // stage A (pre-swizzled bf16) -> LDS, linear, 4 x 16B per thread
#pragma unroll
        for (int i = 0; i < 4; i++){
            const unsigned short* g = Aswz + kc * 16384 + t * 8 + i * 4096;
            unsigned short* l = Atile + t * 8 + i * 4096;
            __builtin_amdgcn_global_load_lds(
                (const __attribute__((address_space(1))) unsigned int*)g,
                (__attribute__((address_space(3))) unsigned int*)l, 16, 0, 0);
        }
        // stage B: f32 -> ssq -> bf16, XOR-swizzled ds_write
        float4 bv[4];
#pragma unroll
        for (int j = 0; j < 4; j++)
            bv[j] = *(const float4*)(rowp + kc * 64 + (q4 + 4 * j) * 4);
#pragma unroll
        for (int j = 0; j < 4; j++){
            ssq += bv[j].x*bv[j].x + bv[j].y*bv[j].y + bv[j].z*bv[j].z + bv[j].w*bv[j].w;
            int idx = q4 + 4 * j;
            int slot = (idx >> 1) ^ (r & 7);
            unsigned int lo = (unsigned int)f2bf(bv[j].x) | ((unsigned int)f2bf(bv[j].y) << 16);
            unsigned int hi = (unsigned int)f2bf(bv[j].z) | ((unsigned int)f2bf(bv[j].w) << 16);
            uint2 pk; pk.x = lo; pk.y = hi;
            *(uint2*)&Btile[r * 64 + slot * 8 + (idx & 1) * 4] = pk;
        }
        __syncthreads();
        // MFMA over this K-chunk
#pragma unroll
        for (int ks = 0; ks < 2; ks++){
            int slot = (ks * 4 + fg) ^ (frow & 7);
            short8 af[4], bfr[4];
#pragma unroll
            for (int fm = 0; fm < 4; fm++)
                af[fm] = *(const short8*)&Atile[(wm * 64 + fm * 16 + frow) * 64 + slot * 8];
#pragma unroll
            for (int fn = 0; fn < 4; fn++)
                bfr[fn] = *(const short8*)&Btile[(wn * 64 + fn * 16 + frow) * 64 + slot * 8];
#pragma unroll
            for (int fm = 0; fm < 4; fm++)
#pragma unroll
                for (int fn = 0; fn < 4; fn++)
                    acc[fm][fn] = __builtin_amdgcn_mfma_f32_16x16x32_bf16(
                        af[fm], bfr[fn], acc[fm][fn], 0, 0, 0);
        }
    }

    // row-norm scales (per chunk column = B row)
    ssq += __shfl_down(ssq, 1);
    ssq += __shfl_down(ssq, 2);
    if (q4 == 0) invn[r] = 1.0f / fmaxf(sqrtf(ssq), 1e-8f);
    __syncthreads();

    // epilogue: per q-row max & sumexp over this chunk's 128 columns
#pragma unroll
    for (int fm = 0; fm < 4; fm++){
#pragma unroll
        for (int rr = 0; rr < 4; rr++){
            float v[4];
#pragma unroll
            for (int fn = 0; fn < 4; fn++)
                v[fn] = acc[fm][fn][rr] * invn[wn * 64 + fn * 16 + frow] * TEMP_INV;
            float m = fmaxf(fmaxf(v[0], v[1]), fmaxf(v[2], v[3]));
#pragma unroll
            for (int o = 1; o < 16; o <<= 1) m = fmaxf(m, __shfl_xor(m, o));
            float s = __expf(v[0]-m) + __expf(v[1]-m) + __expf(v[2]-m) + __expf(v[3]-m);
#pragma unroll
            for (int o = 1; o < 16; o <<= 1) s += __shfl_xor(s, o);
            if (frow == 0){
                int row = wm * 64 + fm * 16 + fg * 4 + rr;
                redm[wn][row] = m;
                reds[wn][row] = s;
            }
        }
    }
    __syncthreads();
    if (t < 256){
        float m0 = redm[0][t], m1 = redm[1][t];
        float M = fmaxf(m0, m1);
        float S = reds[0][t] * __expf(m0 - M) + reds[1][t] * __expf(m1 - M);
        pmax[qc * 256 + t] = M;
        psum[qc * 256 + t] = S;
    }
}

// ---------------------------------------------------------------------------
// k_lse: per q-row, merge 768 chunk partials -> loss_b = LSE_b - diag_b
// ---------------------------------------------------------------------------
__global__ __launch_bounds__(256) void k_lse(const float* __restrict__ pmax,
                                             const float* __restrict__ psum,
                                             const float* __restrict__ diag,
                                             float* __restrict__ lossb){
    int b = blockIdx.x, t = threadIdx.x;
    float m = -1e30f;
    for (int c = t; c < NCH; c += 256) m = fmaxf(m, pmax[c * 256 + b]);
#pragma unroll
    for (int o = 32; o; o >>= 1) m = fmaxf(m, __shfl_xor(m, o));
    __shared__ float red[4];
    __shared__ float Msh;
    if ((t & 63) == 0) red[t >> 6] = m;
    __syncthreads();
    if (t == 0) Msh = fmaxf(fmaxf(red[0], red[1]), fmaxf(red[2], red[3]));
    __syncthreads();
    float M = Msh;
    float s = 0.f;
    for (int c = t; c < NCH; c += 256) s += psum[c * 256 + b] * __expf(pmax[c * 256 + b] - M);
#pragma unroll
    for (int o = 32; o; o >>= 1) s += __shfl_xor(s, o);
    if ((t & 63) == 0) red[t >> 6] = s;
    __syncthreads();
    if (t == 0) lossb[b] = M + logf(red[0] + red[1] + red[2] + red[3]) - diag[b];
}

__global__ __launch_bounds__(256) void k_red(const float* __restrict__ lossb,
                                             float* __restrict__ out){
    int t = threadIdx.x;
    float v = lossb[t];
#pragma unroll
    for (int o = 32; o; o >>= 1) v += __shfl_xor(v, o);
    __shared__ float red[4];
    if ((t & 63) == 0) red[t >> 6] = v;
    __syncthreads();
    if (t == 0) out[0] = (red[0] + red[1] + red[2] + red[3]) * (1.0f / 256.0f);
}

extern "C" void kernel_launch(void* const* d_in, const int* in_sizes, int n_in,
                              void* d_out, int out_size, void* d_ws, size_t ws_size,
                              hipStream_t stream){
    const float* q  = (const float*)d_in[0];
    const float* k  = (const float*)d_in[1];
    const float* qu = (const float*)d_in[2];
    char* ws = (char*)d_ws;
    // ws layout (bytes): A_swz 0..393216 | qnT ..786432 | diag ..787456
    //                    pmax ..1573888 | psum ..2360320 | lossb ..2361344
    unsigned short* Aswz = (unsigned short*)(ws);
    unsigned short* qnT  = (unsigned short*)(ws + 393216);
    float* diag  = (float*)(ws + 786432);
    float* pmax  = (float*)(ws + 787456);
    float* psum  = (float*)(ws + 1573888);
    float* lossb = (float*)(ws + 2360320);

    k_norm<<<256, 256, 0, stream>>>(q, Aswz, qnT);
    k_main<<<768, 512, 0, stream>>>(k, qu, Aswz, qnT, pmax, psum, diag);
    k_lse<<<256, 256, 0, stream>>>(pmax, psum, diag, lossb);
    k_red<<<1, 256, 0, stream>>>(lossb, (float*)d_out);
}

// Round 4
// 71.242 us; speedup vs baseline: 1.5621x; 1.5621x over previous
//
#include <hip/hip_runtime.h>
#include <hip/hip_bf16.h>

typedef __attribute__((ext_vector_type(8))) short short8;
typedef __attribute__((ext_vector_type(4))) float f32x4;

#define TEMP_INV 20.0f
#define NCH 256

__device__ inline unsigned short f2bf(float f){
    unsigned int u = __builtin_bit_cast(unsigned int, f);
    u += 0x7fffu + ((u >> 16) & 1u);
    return (unsigned short)(u >> 16);
}
__device__ inline float bf2f(unsigned short h){
    unsigned int u = ((unsigned int)h) << 16;
    return __builtin_bit_cast(float, u);
}
__device__ inline unsigned int pk2bf(float a, float b){
    return (unsigned int)f2bf(a) | ((unsigned int)f2bf(b) << 16);
}

#define GLOAD16(src, dst) __builtin_amdgcn_global_load_lds( \
    (const __attribute__((address_space(1))) unsigned int*)(src), \
    (__attribute__((address_space(3))) unsigned int*)(dst), 16, 0, 0)

// ---------------------------------------------------------------------------
// k_norm: normalize query rows -> bf16 A, pre-swizzled per-64-col K-chunk
// tiles [12][256][64] so k_main can global_load_lds linearly.
// ---------------------------------------------------------------------------
__global__ __launch_bounds__(256) void k_norm(const float* __restrict__ q,
                                              unsigned short* __restrict__ Aswz){
    int b = blockIdx.x, t = threadIdx.x;
    const float* qr = q + b * 768;
    float v0 = qr[t], v1 = qr[t + 256], v2 = qr[t + 512];
    float ss = v0*v0 + v1*v1 + v2*v2;
#pragma unroll
    for (int o = 32; o; o >>= 1) ss += __shfl_xor(ss, o);
    __shared__ float red[4];
    if ((t & 63) == 0) red[t >> 6] = ss;
    __syncthreads();
    ss = red[0] + red[1] + red[2] + red[3];
    float inv = 1.0f / fmaxf(sqrtf(ss), 1e-8f);
    float nv[3] = {v0 * inv, v1 * inv, v2 * inv};
#pragma unroll
    for (int j = 0; j < 3; j++){
        int cc = t + 256 * j;
        unsigned short h = f2bf(nv[j]);
        int kc = cc >> 6, kl = cc & 63, g = kl >> 3, e = kl & 7;
        int slot = g ^ (b & 7);
        Aswz[kc * 16384 + b * 64 + slot * 8 + e] = h;
    }
}

// ---------------------------------------------------------------------------
// k_main: 256 blocks x 1024 threads (16 waves, exactly 1 block/CU).
// Block b owns combined columns [257b, 257b+257): 256 via two 256x128 MFMA
// passes (on-the-fly B row-norm), col 257b+256 via distributed bf16 dot.
// Block 0's columns are the keys -> diag for free.
// Pipeline: issue A(s+1)/B(s+1) at top of step s, counted s_waitcnt vmcnt(4)
// (never 0 in main loop), double-buffered Atile, raw barriers + compiler
// fences.
// ---------------------------------------------------------------------------
__global__ __launch_bounds__(1024, 1) void k_main(
        const float* __restrict__ keys,
        const float* __restrict__ queue,
        const unsigned short* __restrict__ Aswz,
        float* __restrict__ pmax,
        float* __restrict__ psum,
        float* __restrict__ diag){
    __shared__ unsigned short Atile[2][16384]; // 64 KB, dbuf [256][64] swizzled
    __shared__ unsigned short Btile[8192];     // 16 KB  [128][64] swizzled
    __shared__ float bxnf[768];
    __shared__ unsigned short bxn16[768];
    __shared__ float invn[128];
    __shared__ float redm[4][256];
    __shared__ float reds[4][256];
    __shared__ float xred[4][256];
    __shared__ float wred[16];
    __shared__ float sxs;

    const int b = blockIdx.x, t = threadIdx.x;
    const int lane = t & 63;
    const int w = t >> 6;                 // 0..15
    const int wm = w >> 2, wn = w & 3;    // 4m x 4n waves, each 64x32
    const int frow = lane & 15, fg = lane >> 4;
    const int c = t >> 3, q8 = t & 7;     // B staging: 8 threads/col

    // ----- prologue: extra column (queue row 257*b), normalized, bf16 ------
    size_t rx = (size_t)b * 257;
    float ssx = 0.f;
    if (t < 768){ float v = queue[rx * 768 + t]; bxnf[t] = v; ssx = v * v; }
#pragma unroll
    for (int o = 32; o; o >>= 1) ssx += __shfl_xor(ssx, o);
    if (lane == 0) wred[w] = ssx;
    __syncthreads();
    if (t == 0){
        float s = 0.f;
#pragma unroll
        for (int i = 0; i < 16; i++) s += wred[i];
        sxs = 1.0f / fmaxf(sqrtf(s), 1e-8f);
    }
    __syncthreads();
    if (t < 768) bxn16[t] = f2bf(bxnf[t] * sxs);
    __syncthreads();

    // ----- B row pointers for the two column halves -----
    long n0 = (long)b * 257 + c;
    long n1 = n0 + 128;
    const float* rp0 = ((n0 < 256) ? (keys + n0 * 768)
                                   : (queue + (size_t)(n0 - 256) * 768)) + q8 * 4;
    const float* rp1 = ((n1 < 256) ? (keys + n1 * 768)
                                   : (queue + (size_t)(n1 - 256) * 768)) + q8 * 4;

    // issue A(s=0) stage + load B(s=0) regs  (4 VMEM ops in flight)
    {
        const unsigned short* gA = Aswz + t * 8;
        GLOAD16(gA, &Atile[0][t * 8]);
        GLOAD16(gA + 8192, &Atile[0][t * 8 + 8192]);
    }
    float4 cb0 = *(const float4*)(rp0);
    float4 cb1 = *(const float4*)(rp0 + 32);

    float Mrun = -1e30f, Srun = 0.f;
    float dx = 0.f;
    const int xrow = t & 255, xk = t >> 8;

    for (int p = 0; p < 2; ++p){
        const float* rp = p ? rp1 : rp0;
        float ssq = 0.f;
        f32x4 acc[4][2];
#pragma unroll
        for (int i = 0; i < 4; i++)
#pragma unroll
            for (int j = 0; j < 2; j++) acc[i][j] = (f32x4)0.f;

        for (int kc = 0; kc < 12; ++kc){
            const int s = p * 12 + kc;
            const bool lastStep = (s == 23);
            float4 nb0 = cb0, nb1 = cb1;
            if (!lastStep){
                // issue next step's A stage + B prefetch BEFORE the wait
                const int sn = s + 1;
                const int kcn = (kc < 11) ? (kc + 1) : 0;
                const unsigned short* gA = Aswz + kcn * 16384 + t * 8;
                unsigned short* lA = &Atile[sn & 1][t * 8];
                GLOAD16(gA, lA);
                GLOAD16(gA + 8192, lA + 8192);
                const float* rpn = (kc < 11) ? rp : rp1;
                nb0 = *(const float4*)(rpn + kcn * 64);
                nb1 = *(const float4*)(rpn + kcn * 64 + 32);
                asm volatile("s_waitcnt vmcnt(4)" ::: "memory");
            } else {
                asm volatile("s_waitcnt vmcnt(0)" ::: "memory");
            }

            // convert + ssq + swizzled ds_write of current B
            {
                float4 u = cb0;
                ssq += u.x*u.x + u.y*u.y + u.z*u.z + u.w*u.w;
                int idx = q8;
                int slot = (idx >> 1) ^ (c & 7);
                uint2 pk;
                pk.x = pk2bf(u.x, u.y);
                pk.y = pk2bf(u.z, u.w);
                *(uint2*)&Btile[c * 64 + slot * 8 + (idx & 1) * 4] = pk;
                u = cb1;
                ssq += u.x*u.x + u.y*u.y + u.z*u.z + u.w*u.w;
                idx = q8 + 8;
                slot = (idx >> 1) ^ (c & 7);
                pk.x = pk2bf(u.x, u.y);
                pk.y = pk2bf(u.z, u.w);
                *(uint2*)&Btile[c * 64 + slot * 8 + (idx & 1) * 4] = pk;
            }
            asm volatile("s_waitcnt lgkmcnt(0)" ::: "memory");
            __builtin_amdgcn_s_barrier();
            asm volatile("" ::: "memory");

            // MFMA over this K-chunk
#pragma unroll
            for (int ks = 0; ks < 2; ++ks){
                short8 af[4], bfv[2];
#pragma unroll
                for (int fm = 0; fm < 4; ++fm){
                    int row = wm * 64 + fm * 16 + frow;
                    int slot = (ks * 4 + fg) ^ (frow & 7);
                    af[fm] = *(const short8*)&Atile[s & 1][row * 64 + slot * 8];
                }
#pragma unroll
                for (int fn = 0; fn < 2; ++fn){
                    int row = wn * 32 + fn * 16 + frow;
                    int slot = (ks * 4 + fg) ^ (frow & 7);
                    bfv[fn] = *(const short8*)&Btile[row * 64 + slot * 8];
                }
#pragma unroll
                for (int fm = 0; fm < 4; ++fm)
#pragma unroll
                    for (int fn = 0; fn < 2; ++fn)
                        acc[fm][fn] = __builtin_amdgcn_mfma_f32_16x16x32_bf16(
                            af[fm], bfv[fn], acc[fm][fn], 0, 0, 0);
            }

            // extra-column dot partials (pass 0 covers all kc once), bf16x8
            if (p == 0){
#pragma unroll
                for (int gi = 0; gi < 2; ++gi){
                    int g = xk * 2 + gi;
                    short8 av = *(const short8*)&Atile[kc & 1][xrow * 64 + (g ^ (xrow & 7)) * 8];
                    short8 xv = *(const short8*)&bxn16[kc * 64 + g * 8];
#pragma unroll
                    for (int e = 0; e < 8; ++e)
                        dx += bf2f((unsigned short)av[e]) * bf2f((unsigned short)xv[e]);
                }
            }

            __builtin_amdgcn_s_barrier();   // Btile free for next ds_write
            asm volatile("" ::: "memory");
            cb0 = nb0; cb1 = nb1;
        }

        // ---- pass epilogue: B-col norms, scale, online-softmax partials ----
        ssq += __shfl_xor(ssq, 1);
        ssq += __shfl_xor(ssq, 2);
        ssq += __shfl_xor(ssq, 4);
        if (q8 == 0) invn[c] = 1.0f / fmaxf(sqrtf(ssq), 1e-8f);
        if (p == 0) xred[xk][xrow] = dx;
        __syncthreads();

#pragma unroll
        for (int fm = 0; fm < 4; ++fm){
#pragma unroll
            for (int rr = 0; rr < 4; ++rr){
                float v0 = acc[fm][0][rr] * invn[wn * 32 + frow] * TEMP_INV;
                float v1 = acc[fm][1][rr] * invn[wn * 32 + 16 + frow] * TEMP_INV;
                int row = wm * 64 + fm * 16 + fg * 4 + rr;
                if (b == 0){
                    int col0 = p * 128 + wn * 32 + frow;
                    if (row == col0)      diag[row] = v0;
                    if (row == col0 + 16) diag[row] = v1;
                }
                float m = fmaxf(v0, v1);
#pragma unroll
                for (int o = 1; o < 16; o <<= 1) m = fmaxf(m, __shfl_xor(m, o));
                float s = __expf(v0 - m) + __expf(v1 - m);
#pragma unroll
                for (int o = 1; o < 16; o <<= 1) s += __shfl_xor(s, o);
                if (frow == 0){ redm[wn][row] = m; reds[wn][row] = s; }
            }
        }
        __syncthreads();
        if (t < 256){
#pragma unroll
            for (int ww = 0; ww < 4; ++ww){
                float m2 = redm[ww][t], s2 = reds[ww][t];
                float M = fmaxf(Mrun, m2);
                Srun = Srun * __expf(Mrun - M) + s2 * __expf(m2 - M);
                Mrun = M;
            }
        }
        __syncthreads();
    }

    // ----- final merge with extra column -----
    if (t < 256){
        float vx = (xred[0][t] + xred[1][t] + xred[2][t] + xred[3][t]) * TEMP_INV;
        float M = fmaxf(Mrun, vx);
        float S = Srun * __expf(Mrun - M) + __expf(vx - M);
        pmax[b * 256 + t] = M;
        psum[b * 256 + t] = S;
    }
}

// ---------------------------------------------------------------------------
// k_lse: per q-row, merge 256 chunk partials -> loss_b = LSE_b - diag_b
// ---------------------------------------------------------------------------
__global__ __launch_bounds__(256) void k_lse(const float* __restrict__ pmax,
                                             const float* __restrict__ psum,
                                             const float* __restrict__ diag,
                                             float* __restrict__ lossb){
    int b = blockIdx.x, t = threadIdx.x;
    float m = -1e30f;
    for (int cc = t; cc < NCH; cc += 256) m = fmaxf(m, pmax[cc * 256 + b]);
#pragma unroll
    for (int o = 32; o; o >>= 1) m = fmaxf(m, __shfl_xor(m, o));
    __shared__ float red[4];
    __shared__ float Msh;
    if ((t & 63) == 0) red[t >> 6] = m;
    __syncthreads();
    if (t == 0) Msh = fmaxf(fmaxf(red[0], red[1]), fmaxf(red[2], red[3]));
    __syncthreads();
    float M = Msh;
    float s = 0.f;
    for (int cc = t; cc < NCH; cc += 256) s += psum[cc * 256 + b] * __expf(pmax[cc * 256 + b] - M);
#pragma unroll
    for (int o = 32; o; o >>= 1) s += __shfl_xor(s, o);
    if ((t & 63) == 0) red[t >> 6] = s;
    __syncthreads();
    if (t == 0) lossb[b] = M + logf(red[0] + red[1] + red[2] + red[3]) - diag[b];
}

__global__ __launch_bounds__(256) void k_red(const float* __restrict__ lossb,
                                             float* __restrict__ out){
    int t = threadIdx.x;
    float v = lossb[t];
#pragma unroll
    for (int o = 32; o; o >>= 1) v += __shfl_xor(v, o);
    __shared__ float red[4];
    if ((t & 63) == 0) red[t >> 6] = v;
    __syncthreads();
    if (t == 0) out[0] = (red[0] + red[1] + red[2] + red[3]) * (1.0f / 256.0f);
}

extern "C" void kernel_launch(void* const* d_in, const int* in_sizes, int n_in,
                              void* d_out, int out_size, void* d_ws, size_t ws_size,
                              hipStream_t stream){
    const float* q  = (const float*)d_in[0];
    const float* k  = (const float*)d_in[1];
    const float* qu = (const float*)d_in[2];
    char* ws = (char*)d_ws;
    // ws layout (bytes): Aswz 0..393216 | diag ..394240 | pmax ..656384
    //                    psum ..918528 | lossb ..919552
    unsigned short* Aswz = (unsigned short*)(ws);
    float* diag  = (float*)(ws + 393216);
    float* pmax  = (float*)(ws + 394240);
    float* psum  = (float*)(ws + 656384);
    float* lossb = (float*)(ws + 918528);

    k_norm<<<256, 256, 0, stream>>>(q, Aswz);
    k_main<<<256, 1024, 0, stream>>>(k, qu, Aswz, pmax, psum, diag);
    k_lse<<<256, 256, 0, stream>>>(pmax, psum, diag, lossb);
    k_red<<<1, 256, 0, stream>>>(lossb, (float*)d_out);
}